// Round 11
// baseline (277.326 us; speedup 1.0000x reference)
//
#include <hip/hip_runtime.h>
#include <hip/hip_bf16.h>
#include <math.h>

#define N_NODES 100000
#define N_EDGES 1600000
#define D 64
#define DOUT 10
#define CAP 64
#define APAD 136     // LDS row stride (bf16): 272B, 16B-aligned
#define NBIN 782     // ceil(N/128) dst-bins
#define ABLK 256     // pass-A blocks
#define ACHUNK 6272  // edges per pass-A block (4-aligned; 256*6272 covers 1.6M w/ guard)
#define SCAP 32      // per-(block,bin) segment capacity: mean 8, P(>32) ~ 1e-11

typedef __attribute__((ext_vector_type(8))) short short8;
typedef __attribute__((ext_vector_type(4))) float f32x4;

__device__ __forceinline__ unsigned short f2bf(float f) {
    __hip_bfloat16 h = __float2bfloat16(f);
    return __builtin_bit_cast(unsigned short, h);
}
__device__ __forceinline__ float blo(unsigned v) { return __builtin_bit_cast(float, v << 16); }
__device__ __forceinline__ float bhi(unsigned v) { return __builtin_bit_cast(float, v & 0xFFFF0000u); }

// ---------------- pass A (+ folded cvt & weight-prep): zero global atomics ----------------
#define PROCE(dv, sv) { int bin = (dv) >> 7; int r = atomicAdd(&hist[bin], 1); \
    if (r < SCAP) ebuf[((size_t)blk * NBIN + bin) * SCAP + r] = ((sv) << 7) | ((dv) & 127); }

__global__ __launch_bounds__(1024) void partA_kernel(
    const int* __restrict__ src, const int* __restrict__ dst,
    int* __restrict__ ebuf, int* __restrict__ counts,
    const float* __restrict__ x, unsigned short* __restrict__ xb,
    const float* __restrict__ W_out0, const float* __restrict__ W_root0,
    const float* __restrict__ W_out1, const float* __restrict__ W_root1,
    const float* __restrict__ W_out2, const float* __restrict__ W_root2,
    unsigned short* __restrict__ Wt0, unsigned short* __restrict__ Wt1,
    unsigned short* __restrict__ Wt2) {
    __shared__ int hist[NBIN];
    int tid = threadIdx.x;
    int blk = blockIdx.x;
    for (int i = tid; i < NBIN; i += 1024) hist[i] = 0;
    __syncthreads();
    int e0 = blk * ACHUNK;
    for (int b = tid; b < ACHUNK / 4; b += 1024) {
        int e = e0 + b * 4;
        if (e + 4 <= N_EDGES) {
            int4 d4 = *(const int4*)&dst[e];
            int4 s4 = *(const int4*)&src[e];
            PROCE(d4.x, s4.x) PROCE(d4.y, s4.y) PROCE(d4.z, s4.z) PROCE(d4.w, s4.w)
        } else {
            for (int k = 0; e + k < N_EDGES && k < 4; ++k) {
                int dv = dst[e + k], sv = src[e + k];
                PROCE(dv, sv)
            }
        }
    }
    __syncthreads();
    for (int i = tid; i < NBIN; i += 1024) {
        int h = hist[i];
        counts[blk * NBIN + i] = h < SCAP ? h : SCAP;
    }

    // ---- folded cvt: x (f32) -> xb (bf16) + zero sentinel row N ----
    const int CTOT = (N_NODES + 1) * D / 4;
    for (int i = blk * 1024 + tid; i < CTOT; i += ABLK * 1024) {
        ushort4 o;
        if (i * 4 < N_NODES * D) {
            float4 v = *(const float4*)&x[i * 4];
            o.x = f2bf(v.x); o.y = f2bf(v.y); o.z = f2bf(v.z); o.w = f2bf(v.w);
        } else {
            o.x = 0; o.y = 0; o.z = 0; o.w = 0;
        }
        *(ushort4*)&xb[i * 4] = o;
    }

    // ---- folded weight prep: Wt[col j][k], k<64: W_out, k>=64: W_root ----
    for (int idx = blk * 1024 + tid; idx < 16384 + 2048; idx += ABLK * 1024) {
        if (idx < 8192) {
            int j = idx >> 7, k = idx & 127;
            Wt0[idx] = f2bf(k < 64 ? W_out0[k * D + j] : W_root0[(k - 64) * D + j]);
        } else if (idx < 16384) {
            int t = idx - 8192;
            int j = t >> 7, k = t & 127;
            Wt1[t] = f2bf(k < 64 ? W_out1[k * D + j] : W_root1[(k - 64) * D + j]);
        } else {
            int t = idx - 16384;
            int j = t >> 7, k = t & 127;
            float v = 0.f;
            if (j < DOUT) v = k < 64 ? W_out2[k * DOUT + j] : W_root2[(k - 64) * DOUT + j];
            Wt2[t] = f2bf(v);
        }
    }
}

// ---------------- pass B: per-bin compaction -> bucket slab + true cnt, coalesced out -------
__global__ __launch_bounds__(256) void partB_kernel(const int* __restrict__ ebuf,
                                                    const int* __restrict__ counts,
                                                    int* __restrict__ cnt,
                                                    int* __restrict__ bucket) {
    __shared__ int lb[128 * CAP];   // 32 KB
    __shared__ int lcnt[128];
    __shared__ int sc[ABLK];
    int tid = threadIdx.x;
    int bin = blockIdx.x;
    for (int i = tid; i < 128 * CAP; i += 256) lb[i] = N_NODES;  // sentinel -> zero row
    if (tid < 128) lcnt[tid] = 0;
    if (tid < ABLK) sc[tid] = counts[tid * NBIN + bin];
    __syncthreads();
    for (int i = tid; i < ABLK * SCAP; i += 256) {
        int seg = i >> 5;              // / SCAP
        int slot = i & (SCAP - 1);
        if (slot < sc[seg]) {
            int v = ebuf[((size_t)seg * NBIN + bin) * SCAP + slot];
            int dloc = v & 127;
            int p = atomicAdd(&lcnt[dloc], 1);        // LDS atomic; true in-degree
            if (p < CAP) lb[dloc * CAP + p] = v >> 7;
        }
    }
    __syncthreads();
    size_t nodeBase = (size_t)bin << 7;
    int lastNode = N_NODES - (int)nodeBase;           // valid dloc < lastNode
    for (int i = tid; i < 128 * CAP / 4; i += 256) {
        int dloc = (i * 4) >> 6;
        if (dloc < lastNode)
            *(int4*)&bucket[nodeBase * CAP + i * 4] = *(const int4*)&lb[i * 4];
    }
    if (tid < 128 && tid < lastNode) cnt[nodeBase + tid] = lcnt[tid];
}

// ---------------- gather: 1 node per 8-lane group, 8 nodes/wave; depth-3 pipeline ----------
__global__ __launch_bounds__(256) void gather_kernel(
    const unsigned short* __restrict__ in, unsigned short* __restrict__ agg,
    const int* __restrict__ cnt, const int* __restrict__ bucket) {
    int tid = threadIdx.x;
    int lane = tid & 63;
    int g = lane >> 3, j = lane & 7;
    int wv = (blockIdx.x * blockDim.x + tid) >> 6;
    int nw = (gridDim.x * blockDim.x) >> 6;
    const int NP = (N_NODES + 8) / 8;   // 12501 packs cover nodes 0..100007

    for (int pr = wv; pr < NP; pr += nw) {
        int n0 = pr * 8;
        int nd = n0 + g;
        int node = nd < N_NODES ? nd : 0;
        int c = nd < N_NODES ? cnt[nd] : 0;
        int cc = c < CAP ? c : CAP;
        const int* __restrict__ brow = &bucket[(size_t)node * CAP];

        float a0 = 0.f, a1 = 0.f, a2 = 0.f, a3 = 0.f,
              a4 = 0.f, a5 = 0.f, a6 = 0.f, a7 = 0.f;
        uint4 rA = {0, 0, 0, 0}, rB = {0, 0, 0, 0}, rC = {0, 0, 0, 0};
        if (cc > 0) rA = *(const uint4*)&in[(size_t)brow[0] * D + j * 8];
        if (cc > 1) rB = *(const uint4*)&in[(size_t)brow[1] * D + j * 8];
        if (cc > 2) rC = *(const uint4*)&in[(size_t)brow[2] * D + j * 8];
        for (int it = 0; it < cc; ++it) {
            uint4 r = rA;
            rA = rB; rB = rC;
            if (it + 3 < cc) rC = *(const uint4*)&in[(size_t)brow[it + 3] * D + j * 8];
            a0 += blo(r.x); a1 += bhi(r.x);
            a2 += blo(r.y); a3 += bhi(r.y);
            a4 += blo(r.z); a5 += bhi(r.z);
            a6 += blo(r.w); a7 += bhi(r.w);
        }
        if (nd <= N_NODES) {   // sentinel row N written as zeros (c=0 -> acc=0)
            float dinv = 1.0f / (float)(c > 0 ? c : 1);
            uint4 pk;
            pk.x = (unsigned)f2bf(a0 * dinv) | ((unsigned)f2bf(a1 * dinv) << 16);
            pk.y = (unsigned)f2bf(a2 * dinv) | ((unsigned)f2bf(a3 * dinv) << 16);
            pk.z = (unsigned)f2bf(a4 * dinv) | ((unsigned)f2bf(a5 * dinv) << 16);
            pk.w = (unsigned)f2bf(a6 * dinv) | ((unsigned)f2bf(a7 * dinv) << 16);
            *(uint4*)&agg[(size_t)nd * D + j * 8] = pk;
        }
    }
}

// ---------------- dense hidden GEMM: C = relu([agg|x] @ Wcat + b), 64-node tile ----------------
__global__ __launch_bounds__(256) void gemm_hidden_kernel(
    const unsigned short* __restrict__ agg, const unsigned short* __restrict__ xin,
    unsigned short* __restrict__ out, const unsigned short* __restrict__ Wt_g,
    const float* __restrict__ bias_v) {
    __shared__ __align__(16) unsigned short Wt[64 * APAD];
    int tid = threadIdx.x;
#pragma unroll
    for (int i = 0; i < 4; ++i) {
        int e = (tid + i * 256) * 8;
        uint4 v = *(const uint4*)&Wt_g[e];
        *(uint4*)&Wt[(e >> 7) * APAD + (e & 127)] = v;
    }
    __syncthreads();

    int lane = tid & 63, w = tid >> 6;
    int r16 = lane & 15, g4 = lane >> 4;
    int base = blockIdx.x * 64;
    int arow = base + w * 16 + r16;
    int nd = arow < N_NODES ? arow : N_NODES;   // clamp to sentinel zero row

    f32x4 acc[4] = {{0.f,0.f,0.f,0.f},{0.f,0.f,0.f,0.f},{0.f,0.f,0.f,0.f},{0.f,0.f,0.f,0.f}};
#pragma unroll
    for (int ks = 0; ks < 4; ++ks) {
        int koff = ks * 32 + g4 * 8;
        short8 a;
        if (ks < 2) a = *(const short8*)&agg[(size_t)nd * D + koff];
        else        a = *(const short8*)&xin[(size_t)nd * D + (koff - 64)];
#pragma unroll
        for (int n = 0; n < 4; ++n) {
            short8 b = *(const short8*)&Wt[(n * 16 + r16) * APAD + koff];
            acc[n] = __builtin_amdgcn_mfma_f32_16x16x32_bf16(a, b, acc[n], 0, 0, 0);
        }
    }
#pragma unroll
    for (int n = 0; n < 4; ++n) {
        int col = n * 16 + r16;
        float bias = bias_v[col];
#pragma unroll
        for (int r = 0; r < 4; ++r) {
            int node = base + w * 16 + g4 * 4 + r;
            if (node <= N_NODES) {   // row N: keep sentinel zero (bias must not leak in)
                float v = node < N_NODES ? fmaxf(acc[n][r] + bias, 0.f) : 0.f;
                out[(size_t)node * D + col] = f2bf(v);
            }
        }
    }
}

// ---------------- output GEMM (64->10) + fused log_softmax ----------------
__global__ __launch_bounds__(256) void gemm_out_kernel(
    const unsigned short* __restrict__ agg, const unsigned short* __restrict__ xin,
    float* __restrict__ out, const unsigned short* __restrict__ Wt_g,
    const float* __restrict__ bias_v) {
    __shared__ __align__(16) unsigned short Wt[16 * APAD];
    int tid = threadIdx.x;
    {
        int e = tid * 8;
        uint4 v = *(const uint4*)&Wt_g[e];
        *(uint4*)&Wt[(e >> 7) * APAD + (e & 127)] = v;
    }
    __syncthreads();

    int lane = tid & 63, w = tid >> 6;
    int r16 = lane & 15, g4 = lane >> 4;
    int base = blockIdx.x * 64;
    int arow = base + w * 16 + r16;
    int nd = arow < N_NODES ? arow : N_NODES;

    f32x4 acc = {0.f, 0.f, 0.f, 0.f};
#pragma unroll
    for (int ks = 0; ks < 4; ++ks) {
        int koff = ks * 32 + g4 * 8;
        short8 a;
        if (ks < 2) a = *(const short8*)&agg[(size_t)nd * D + koff];
        else        a = *(const short8*)&xin[(size_t)nd * D + (koff - 64)];
        short8 b = *(const short8*)&Wt[r16 * APAD + koff];
        acc = __builtin_amdgcn_mfma_f32_16x16x32_bf16(a, b, acc, 0, 0, 0);
    }
    float bias = r16 < DOUT ? bias_v[r16] : -1e30f;   // pad cols -> exp()=0
#pragma unroll
    for (int r = 0; r < 4; ++r) {
        float v = acc[r] + bias;
        float m = v;
        m = fmaxf(m, __shfl_xor(m, 1, 16));
        m = fmaxf(m, __shfl_xor(m, 2, 16));
        m = fmaxf(m, __shfl_xor(m, 4, 16));
        m = fmaxf(m, __shfl_xor(m, 8, 16));
        float e = expf(v - m);
        float s = e;
        s += __shfl_xor(s, 1, 16);
        s += __shfl_xor(s, 2, 16);
        s += __shfl_xor(s, 4, 16);
        s += __shfl_xor(s, 8, 16);
        int node = base + w * 16 + g4 * 4 + r;
        if (node < N_NODES && r16 < DOUT)
            out[(size_t)node * DOUT + r16] = v - m - logf(s);
    }
}

extern "C" void kernel_launch(void* const* d_in, const int* in_sizes, int n_in,
                              void* d_out, int out_size, void* d_ws, size_t ws_size,
                              hipStream_t stream) {
    const float* x       = (const float*)d_in[0];
    const int*   ei      = (const int*)d_in[1];
    const int*   src     = ei;            // edge_index[0]
    const int*   dst     = ei + N_EDGES;  // edge_index[1]
    const float* W_out0  = (const float*)d_in[2];
    const float* b0      = (const float*)d_in[3];
    const float* W_root0 = (const float*)d_in[4];
    const float* W_out1  = (const float*)d_in[5];
    const float* b1      = (const float*)d_in[6];
    const float* W_root1 = (const float*)d_in[7];
    const float* W_out2  = (const float*)d_in[8];
    const float* b2      = (const float*)d_in[9];
    const float* W_root2 = (const float*)d_in[10];
    float* outp = (float*)d_out;

    // ws (256 MiB available; ~91 MB used, NO aliasing):
    //   xb | h0 | h1 ((N+1)*64 bf16) | Wt0|Wt1 (8192) | Wt2 (2048) | cnt (N i32)
    //   | bucket (N*64 i32) | ebuf (256*782*32 i32 = 25.6MB) | counts (0.8MB)
    const size_t ROWS = (size_t)(N_NODES + 1) * D;
    unsigned short* xb  = (unsigned short*)d_ws;
    unsigned short* h0  = xb + ROWS;
    unsigned short* h1  = h0 + ROWS;
    unsigned short* Wt0 = h1 + ROWS;
    unsigned short* Wt1 = Wt0 + 8192;
    unsigned short* Wt2 = Wt1 + 8192;
    int* cnt    = (int*)(Wt2 + 2048);
    int* bucket = cnt + N_NODES;
    int* ebuf   = bucket + (size_t)N_NODES * CAP;
    int* counts = ebuf + (size_t)ABLK * NBIN * SCAP;

    partA_kernel<<<ABLK, 1024, 0, stream>>>(src, dst, ebuf, counts, x, xb,
                                            W_out0, W_root0, W_out1, W_root1,
                                            W_out2, W_root2, Wt0, Wt1, Wt2);
    partB_kernel<<<NBIN, 256, 0, stream>>>(ebuf, counts, cnt, bucket);

    const int GB = 2048;                      // 8 blocks/CU residency for 64-VGPR gather
    const int tiles = (N_NODES + 63) / 64;    // 1563 GEMM tiles
    // layer 0: agg -> h1 (free), gemm -> h0
    gather_kernel<<<GB, 256, 0, stream>>>(xb, h1, cnt, bucket);
    gemm_hidden_kernel<<<tiles, 256, 0, stream>>>(h1, xb, h0, Wt0, b0);
    // layer 1: agg -> xb (free), gemm -> h1
    gather_kernel<<<GB, 256, 0, stream>>>(h0, xb, cnt, bucket);
    gemm_hidden_kernel<<<tiles, 256, 0, stream>>>(xb, h0, h1, Wt1, b1);
    // layer 2: agg -> h0 (free), gemm -> out
    gather_kernel<<<GB, 256, 0, stream>>>(h1, h0, cnt, bucket);
    gemm_out_kernel<<<tiles, 256, 0, stream>>>(h0, h1, outp, Wt2, b2);
}